// Round 3
// baseline (1070.684 us; speedup 1.0000x reference)
//
#include <hip/hip_runtime.h>
#include <stdint.h>

#define S_LEN 2048
#define D_HEAD 64
#define NBH 16
#define NROWS (NBH * S_LEN)               // 32768 attention rows
#define CTX_ELEMS (NBH * S_LEN * D_HEAD)  // 2,097,152 floats

// d_out layout: [ctx 8MB][attn 268MB]. psum scratch lives in the ctx region
// (written by qk, consumed by row_inv, then ctx is overwritten by pv).
// ws layout: [inv 128KB][flag 4B] — tiny on purpose.

// ---------------------------------------------------------------------------
// Mask dtype detection: jax bool may arrive as 1B bools or int32. Scan first
// 16384 words; any word > 1 => byte layout (p~0.27/word that an upper byte is
// set => certain over 16K words). int32 layout only ever has words 0/1.
// ---------------------------------------------------------------------------
__global__ void detect_mask_kernel(const uint32_t* __restrict__ m, int* flag) {
  __shared__ int any;
  if (threadIdx.x == 0) any = 0;
  __syncthreads();
  int local = 0;
  for (int i = threadIdx.x; i < 16384; i += 256)
    if (m[i] > 1u) local = 1;
  if (local) atomicOr(&any, 1);
  __syncthreads();
  if (threadIdx.x == 0) *flag = any;
}

// ---------------------------------------------------------------------------
// Kernel 1: e = exp((Q.K^T)/8) (0 where masked), unnormalized, into attn
// region; plus per-(row, 128-col-block) partial sums into psum (ctx region).
// 128x128 tile, 256 threads, 8x8 micro. Thread's 8 cols are split
// {4j..4j+3, 64+4j..64+4j+3}: the 16 j-lanes then read 64 consecutive floats
// per b128 => 2-way bank aliasing (free) instead of 4-way at tx=8j.
// ---------------------------------------------------------------------------
__global__ __launch_bounds__(256, 2) void qk_exp_kernel(
    const float* __restrict__ Q, const float* __restrict__ K,
    const void* __restrict__ mask, float* __restrict__ e_out,
    float* __restrict__ psum, const int* __restrict__ mflag) {
  __shared__ float Qs[D_HEAD][132];
  __shared__ float Ks[D_HEAD][132];
  const int bh = blockIdx.z;
  const int mBase = blockIdx.y * 128;
  const int nBase = blockIdx.x * 128;
  const float* __restrict__ Qb = Q + (size_t)bh * S_LEN * D_HEAD;
  const float* __restrict__ Kb = K + (size_t)bh * S_LEN * D_HEAD;
  float* __restrict__ Eb = e_out + (size_t)bh * S_LEN * S_LEN;
  const int tid = threadIdx.x;
  const int maskIsBytes = *mflag;

#pragma unroll
  for (int i = 0; i < 8; ++i) {
    const int f4 = tid + i * 256;  // 0..2047
    const int row = f4 >> 4;       // 16 float4 per 64-float row
    const int d0 = (f4 & 15) << 2;
    const float4 qv = *reinterpret_cast<const float4*>(
        Qb + (size_t)(mBase + row) * D_HEAD + d0);
    const float4 kv = *reinterpret_cast<const float4*>(
        Kb + (size_t)(nBase + row) * D_HEAD + d0);
    Qs[d0 + 0][row] = qv.x; Qs[d0 + 1][row] = qv.y;
    Qs[d0 + 2][row] = qv.z; Qs[d0 + 3][row] = qv.w;
    Ks[d0 + 0][row] = kv.x; Ks[d0 + 1][row] = kv.y;
    Ks[d0 + 2][row] = kv.z; Ks[d0 + 3][row] = kv.w;
  }
  __syncthreads();

  const int ty = (tid >> 4) << 3;  // rows: 8 contiguous (broadcast reads)
  const int cj = (tid & 15) << 2;  // col split: cj and 64+cj
  float acc[8][8] = {};
#pragma unroll 4
  for (int d = 0; d < D_HEAD; ++d) {
    const float4 q0 = *reinterpret_cast<const float4*>(&Qs[d][ty]);
    const float4 q1 = *reinterpret_cast<const float4*>(&Qs[d][ty + 4]);
    const float4 kl = *reinterpret_cast<const float4*>(&Ks[d][cj]);
    const float4 kh = *reinterpret_cast<const float4*>(&Ks[d][64 + cj]);
    const float qv[8] = {q0.x, q0.y, q0.z, q0.w, q1.x, q1.y, q1.z, q1.w};
    const float kv[8] = {kl.x, kl.y, kl.z, kl.w, kh.x, kh.y, kh.z, kh.w};
#pragma unroll
    for (int i = 0; i < 8; ++i)
#pragma unroll
      for (int j = 0; j < 8; ++j)
        acc[i][j] = fmaf(qv[i], kv[j], acc[i][j]);
  }

  const float scale = 0.125f;  // 1/sqrt(64)
#pragma unroll
  for (int i = 0; i < 8; ++i) {
    const int row = mBase + ty + i;  // local row in [0,2048)
    float e[8];
    if (maskIsBytes) {
      const unsigned char* mrow =
          (const unsigned char*)mask + ((size_t)bh * S_LEN + row) * S_LEN;
      const uint32_t ml = *reinterpret_cast<const uint32_t*>(mrow + nBase + cj);
      const uint32_t mh =
          *reinterpret_cast<const uint32_t*>(mrow + nBase + 64 + cj);
#pragma unroll
      for (int j = 0; j < 4; ++j) {
        e[j] = ((ml >> (8 * j)) & 0xffu) ? 0.0f : __expf(acc[i][j] * scale);
        e[4 + j] =
            ((mh >> (8 * j)) & 0xffu) ? 0.0f : __expf(acc[i][4 + j] * scale);
      }
    } else {
      const int* mrow = (const int*)mask + ((size_t)bh * S_LEN + row) * S_LEN;
      const int4 m0 = *reinterpret_cast<const int4*>(mrow + nBase + cj);
      const int4 m1 = *reinterpret_cast<const int4*>(mrow + nBase + 64 + cj);
      const int mi[8] = {m0.x, m0.y, m0.z, m0.w, m1.x, m1.y, m1.z, m1.w};
#pragma unroll
      for (int j = 0; j < 8; ++j)
        e[j] = mi[j] ? 0.0f : __expf(acc[i][j] * scale);
    }
    const float4 o0 = {e[0], e[1], e[2], e[3]};
    const float4 o1 = {e[4], e[5], e[6], e[7]};
    float* dst = Eb + (size_t)row * S_LEN + nBase;
    *reinterpret_cast<float4*>(dst + cj) = o0;
    *reinterpret_cast<float4*>(dst + 64 + cj) = o1;

    float r = (e[0] + e[1] + e[2] + e[3]) + (e[4] + e[5] + e[6] + e[7]);
    r += __shfl_xor(r, 1, 64);
    r += __shfl_xor(r, 2, 64);
    r += __shfl_xor(r, 4, 64);
    r += __shfl_xor(r, 8, 64);
    if ((tid & 15) == 0)
      psum[((size_t)bh * S_LEN + row) * 16 + blockIdx.x] = r;
  }
}

// ---------------------------------------------------------------------------
// Kernel 2: inv[row] = 1 / sum(psum[row][0..15])
// ---------------------------------------------------------------------------
__global__ __launch_bounds__(256) void row_inv_kernel(
    const float* __restrict__ psum, float* __restrict__ inv) {
  const int row = blockIdx.x * 256 + threadIdx.x;
  const float4* p = reinterpret_cast<const float4*>(psum + (size_t)row * 16);
  const float4 a = p[0], b = p[1], c = p[2], d = p[3];
  const float s = ((a.x + a.y) + (a.z + a.w)) + ((b.x + b.y) + (b.z + b.w)) +
                  ((c.x + c.y) + (c.z + c.w)) + ((d.x + d.y) + (d.z + d.w));
  inv[row] = 1.0f / s;
}

// ---------------------------------------------------------------------------
// Kernel 3: PV fused with normalization + attn write-back. Row-per-lane:
// block = 64 rows x full D, 4 waves; wave w covers k in [w*512,(w+1)*512).
// Per k-tile(32): wave stages P 64x32 coalesced (normalize + write back
// normalized attn + transpose to its private LDS buf [32][68] => 2-way-free
// compute reads). Inner: e = Pl[k][lane]; V[k][0..63] via lane-uniform
// float4 loads (HW dedups to one 16B txn, L1/L2-resident); 64 indep fmaf.
// No barriers in main loop (waves independent). End: 2-round LDS combine of
// the 4 k-partials, coalesced ctx store. No atomics, no global partials.
// ---------------------------------------------------------------------------
__global__ __launch_bounds__(256, 2) void pv_kernel(
    float* __restrict__ attn, const float* __restrict__ V,
    const float* __restrict__ inv, float* __restrict__ ctx) {
  __shared__ float Pl[4][32][68];  // per-wave transpose buffer, 34.8 KB
  __shared__ float inv_s[64];
  const int bh = blockIdx.y;
  const int mb = blockIdx.x * 64;
  const int tid = threadIdx.x;
  const int w = tid >> 6;
  const int lane = tid & 63;
  float* __restrict__ Ab = attn + (size_t)bh * S_LEN * S_LEN;
  const float* __restrict__ Vb = V + (size_t)bh * S_LEN * D_HEAD;

  if (tid < 64) inv_s[tid] = inv[(size_t)bh * S_LEN + mb + tid];
  __syncthreads();

  float acc[D_HEAD] = {};
  const int kBeg = w * (S_LEN / 4);
  for (int kt = kBeg; kt < kBeg + S_LEN / 4; kt += 32) {
    // stage P 64 rows x 32 k: normalize, write back, transpose into Pl[w]
#pragma unroll
    for (int t = 0; t < 8; ++t) {
      const int f4i = t * 64 + lane;  // 0..511
      const int r = f4i >> 3;         // 0..63
      const int c4 = (f4i & 7) << 2;  // 0..28
      float* gp = Ab + (size_t)(mb + r) * S_LEN + kt + c4;
      float4 e = *reinterpret_cast<const float4*>(gp);
      const float sc = inv_s[r];
      e.x *= sc; e.y *= sc; e.z *= sc; e.w *= sc;
      *reinterpret_cast<float4*>(gp) = e;  // normalized attn write-back
      Pl[w][c4 + 0][r] = e.x; Pl[w][c4 + 1][r] = e.y;
      Pl[w][c4 + 2][r] = e.z; Pl[w][c4 + 3][r] = e.w;
    }
    // compute: per k, broadcast V row, lane-private e
#pragma unroll 2
    for (int k = 0; k < 32; ++k) {
      const float e = Pl[w][k][lane];
      const float4* __restrict__ vp =
          reinterpret_cast<const float4*>(Vb + (size_t)(kt + k) * D_HEAD);
#pragma unroll
      for (int d4 = 0; d4 < 16; ++d4) {
        const float4 v = vp[d4];
        acc[4 * d4 + 0] = fmaf(e, v.x, acc[4 * d4 + 0]);
        acc[4 * d4 + 1] = fmaf(e, v.y, acc[4 * d4 + 1]);
        acc[4 * d4 + 2] = fmaf(e, v.z, acc[4 * d4 + 2]);
        acc[4 * d4 + 3] = fmaf(e, v.w, acc[4 * d4 + 3]);
      }
    }
  }

  // combine the 4 per-wave k-partials via LDS overlay, 2 rounds of 32 rows
  float* cb = reinterpret_cast<float*>(Pl);  // 8704 floats >= 8192 needed
  for (int half = 0; half < 2; ++half) {
    __syncthreads();
    if ((lane >> 5) == half) {
      const int r32 = lane & 31;
#pragma unroll
      for (int d4 = 0; d4 < 16; ++d4) {
        float4 a = {acc[4 * d4], acc[4 * d4 + 1], acc[4 * d4 + 2],
                    acc[4 * d4 + 3]};
        *reinterpret_cast<float4*>(&cb[((w * 32 + r32) << 6) + 4 * d4]) = a;
      }
    }
    __syncthreads();
    const int r32 = tid >> 3;       // 0..31
    const int d0 = (tid & 7) << 3;  // 0..56
    float4 s0 = {0, 0, 0, 0}, s1 = {0, 0, 0, 0};
#pragma unroll
    for (int ww = 0; ww < 4; ++ww) {
      const float4 a =
          *reinterpret_cast<const float4*>(&cb[((ww * 32 + r32) << 6) + d0]);
      const float4 b = *reinterpret_cast<const float4*>(
          &cb[((ww * 32 + r32) << 6) + d0 + 4]);
      s0.x += a.x; s0.y += a.y; s0.z += a.z; s0.w += a.w;
      s1.x += b.x; s1.y += b.y; s1.z += b.z; s1.w += b.w;
    }
    float* dst =
        ctx + ((size_t)bh * S_LEN + mb + half * 32 + r32) * D_HEAD + d0;
    *reinterpret_cast<float4*>(dst) = s0;
    *reinterpret_cast<float4*>(dst + 4) = s1;
  }
}

extern "C" void kernel_launch(void* const* d_in, const int* in_sizes, int n_in,
                              void* d_out, int out_size, void* d_ws, size_t ws_size,
                              hipStream_t stream) {
  const float* Q = (const float*)d_in[0];
  const float* K = (const float*)d_in[1];
  const float* V = (const float*)d_in[2];
  const void* mask = d_in[3];  // jax bool: bytes or int32 — auto-detected

  float* ctx = (float*)d_out;               // [B,H,S,D]
  float* attn = (float*)d_out + CTX_ELEMS;  // [B,H,S,S]
  float* psum = ctx;                        // 2MB scratch inside ctx region

  float* inv = (float*)d_ws;                       // 128 KB
  int* mflag = (int*)((char*)d_ws + NROWS * 4);    // 4 B

  detect_mask_kernel<<<1, 256, 0, stream>>>((const uint32_t*)mask, mflag);
  qk_exp_kernel<<<dim3(S_LEN / 128, S_LEN / 128, NBH), 256, 0, stream>>>(
      Q, K, mask, attn, psum, mflag);
  row_inv_kernel<<<NROWS / 256, 256, 0, stream>>>(psum, inv);
  pv_kernel<<<dim3(S_LEN / 64, NBH), 256, 0, stream>>>(attn, V, inv, ctx);
}

// Round 4
// 665.820 us; speedup vs baseline: 1.6081x; 1.6081x over previous
//
#include <hip/hip_runtime.h>
#include <stdint.h>

#define S_LEN 2048
#define D_HEAD 64
#define NBH 16
#define NROWS (NBH * S_LEN)               // 32768 attention rows
#define CTX_ELEMS (NBH * S_LEN * D_HEAD)  // 2,097,152 floats

// d_out layout: [ctx 8MB][attn 268MB]. qk's psum scratch lives in the ctx
// region (consumed by row_inv before pv/combine overwrite ctx).
// ws layout: [inv 128KB][flag 4B][pad to 256B][pv k-split partials split*8MB]

// ---------------------------------------------------------------------------
// Mask dtype detection: jax bool may arrive as 1B bools or int32. Any 32-bit
// word > 1 in the first 16K words => byte layout.
// ---------------------------------------------------------------------------
__global__ void detect_mask_kernel(const uint32_t* __restrict__ m, int* flag) {
  __shared__ int any;
  if (threadIdx.x == 0) any = 0;
  __syncthreads();
  int local = 0;
  for (int i = threadIdx.x; i < 16384; i += 256)
    if (m[i] > 1u) local = 1;
  if (local) atomicOr(&any, 1);
  __syncthreads();
  if (threadIdx.x == 0) *flag = any;
}

// ---------------------------------------------------------------------------
// Kernel 1: e = exp((Q.K^T)/8) (0 where masked), unnormalized, into the attn
// region; per-(row, 128-col-block) partial sums into psum (ctx region).
// 128x128 tile, 256 threads, 8x8 micro. K-dim staged in TWO 32-d phases so
// LDS is 33.8 KB -> 4 blocks/CU (was 67.6 KB -> 2 blocks/CU, latency-bound).
// ---------------------------------------------------------------------------
__global__ __launch_bounds__(256, 3) void qk_exp_kernel(
    const float* __restrict__ Q, const float* __restrict__ K,
    const void* __restrict__ mask, float* __restrict__ e_out,
    float* __restrict__ psum, const int* __restrict__ mflag) {
  __shared__ float Qs[32][132];
  __shared__ float Ks[32][132];
  const int bh = blockIdx.z;
  const int mBase = blockIdx.y * 128;
  const int nBase = blockIdx.x * 128;
  const float* __restrict__ Qb = Q + (size_t)bh * S_LEN * D_HEAD;
  const float* __restrict__ Kb = K + (size_t)bh * S_LEN * D_HEAD;
  float* __restrict__ Eb = e_out + (size_t)bh * S_LEN * S_LEN;
  const int tid = threadIdx.x;
  const int maskIsBytes = *mflag;

  const int ty = (tid >> 4) << 3;  // rows: 8 contiguous (16-lane broadcast)
  const int cj = (tid & 15) << 2;  // cols: cj and 64+cj (2-way-free b128)
  float acc[8][8] = {};

#pragma unroll
  for (int ph = 0; ph < 2; ++ph) {
    const int dBase = ph * 32;
    if (ph) __syncthreads();  // protect LDS from previous phase's readers
    // stage 128 rows x 32 d of Q and K, transposed [d][row]
#pragma unroll
    for (int i = 0; i < 4; ++i) {
      const int f4 = tid + i * 256;  // 0..1023
      const int row = f4 >> 3;       // 8 float4 per 32-float row
      const int d0 = (f4 & 7) << 2;
      const float4 qv = *reinterpret_cast<const float4*>(
          Qb + (size_t)(mBase + row) * D_HEAD + dBase + d0);
      const float4 kv = *reinterpret_cast<const float4*>(
          Kb + (size_t)(nBase + row) * D_HEAD + dBase + d0);
      Qs[d0 + 0][row] = qv.x; Qs[d0 + 1][row] = qv.y;
      Qs[d0 + 2][row] = qv.z; Qs[d0 + 3][row] = qv.w;
      Ks[d0 + 0][row] = kv.x; Ks[d0 + 1][row] = kv.y;
      Ks[d0 + 2][row] = kv.z; Ks[d0 + 3][row] = kv.w;
    }
    __syncthreads();
#pragma unroll 4
    for (int d = 0; d < 32; ++d) {
      const float4 q0 = *reinterpret_cast<const float4*>(&Qs[d][ty]);
      const float4 q1 = *reinterpret_cast<const float4*>(&Qs[d][ty + 4]);
      const float4 kl = *reinterpret_cast<const float4*>(&Ks[d][cj]);
      const float4 kh = *reinterpret_cast<const float4*>(&Ks[d][64 + cj]);
      const float qv[8] = {q0.x, q0.y, q0.z, q0.w, q1.x, q1.y, q1.z, q1.w};
      const float kv[8] = {kl.x, kl.y, kl.z, kl.w, kh.x, kh.y, kh.z, kh.w};
#pragma unroll
      for (int i = 0; i < 8; ++i)
#pragma unroll
        for (int j = 0; j < 8; ++j)
          acc[i][j] = fmaf(qv[i], kv[j], acc[i][j]);
    }
  }

  const float scale = 0.125f;  // 1/sqrt(64)
#pragma unroll
  for (int i = 0; i < 8; ++i) {
    const int row = mBase + ty + i;
    float e[8];
    if (maskIsBytes) {
      const unsigned char* mrow =
          (const unsigned char*)mask + ((size_t)bh * S_LEN + row) * S_LEN;
      const uint32_t ml = *reinterpret_cast<const uint32_t*>(mrow + nBase + cj);
      const uint32_t mh =
          *reinterpret_cast<const uint32_t*>(mrow + nBase + 64 + cj);
#pragma unroll
      for (int j = 0; j < 4; ++j) {
        e[j] = ((ml >> (8 * j)) & 0xffu) ? 0.0f : __expf(acc[i][j] * scale);
        e[4 + j] =
            ((mh >> (8 * j)) & 0xffu) ? 0.0f : __expf(acc[i][4 + j] * scale);
      }
    } else {
      const int* mrow = (const int*)mask + ((size_t)bh * S_LEN + row) * S_LEN;
      const int4 m0 = *reinterpret_cast<const int4*>(mrow + nBase + cj);
      const int4 m1 = *reinterpret_cast<const int4*>(mrow + nBase + 64 + cj);
      const int mi[8] = {m0.x, m0.y, m0.z, m0.w, m1.x, m1.y, m1.z, m1.w};
#pragma unroll
      for (int j = 0; j < 8; ++j)
        e[j] = mi[j] ? 0.0f : __expf(acc[i][j] * scale);
    }
    const float4 o0 = {e[0], e[1], e[2], e[3]};
    const float4 o1 = {e[4], e[5], e[6], e[7]};
    float* dst = Eb + (size_t)row * S_LEN + nBase;
    *reinterpret_cast<float4*>(dst + cj) = o0;
    *reinterpret_cast<float4*>(dst + 64 + cj) = o1;

    float r = (e[0] + e[1] + e[2] + e[3]) + (e[4] + e[5] + e[6] + e[7]);
    r += __shfl_xor(r, 1, 64);
    r += __shfl_xor(r, 2, 64);
    r += __shfl_xor(r, 4, 64);
    r += __shfl_xor(r, 8, 64);
    if ((tid & 15) == 0)
      psum[((size_t)bh * S_LEN + row) * 16 + blockIdx.x] = r;
  }
}

// ---------------------------------------------------------------------------
// Kernel 2: inv[row] = 1 / sum(psum[row][0..15])
// ---------------------------------------------------------------------------
__global__ __launch_bounds__(256) void row_inv_kernel(
    const float* __restrict__ psum, float* __restrict__ inv) {
  const int row = blockIdx.x * 256 + threadIdx.x;
  const float4* p = reinterpret_cast<const float4*>(psum + (size_t)row * 16);
  const float4 a = p[0], b = p[1], c = p[2], d = p[3];
  const float s = ((a.x + a.y) + (a.z + a.w)) + ((b.x + b.y) + (b.z + b.w)) +
                  ((c.x + c.y) + (c.z + c.w)) + ((d.x + d.y) + (d.z + d.w));
  inv[row] = 1.0f / s;
}

// ---------------------------------------------------------------------------
// Kernel 3: PV GEMM fused with normalization + normalized-attn write-back.
// Tile M=128 x N=64(full D), K-step 32, 256 threads, 8x4 micro. V staged in
// LDS (no uniform global loads in the hot loop — round-3's 2700cy/k killer).
// blockIdx.z = k-split chunk; partials go to ws (or straight to ctx if
// split==1). LDS 26 KB -> 4 blocks/CU; grid 16*16*split.
// ---------------------------------------------------------------------------
__global__ __launch_bounds__(256, 4) void pv_kernel(
    float* __restrict__ attn, const float* __restrict__ V,
    const float* __restrict__ inv, float* __restrict__ part, int kLen) {
  __shared__ float Es[32][132];  // [k][m] transposed, 16.9 KB
  __shared__ float Vs[32][68];   // [k][d] natural, 8.7 KB
  __shared__ float inv_s[128];
  const int bh = blockIdx.y;
  const int mBase = blockIdx.x * 128;
  const int z = blockIdx.z;
  float* __restrict__ Ab = attn + (size_t)bh * S_LEN * S_LEN;
  const float* __restrict__ Vb = V + (size_t)bh * S_LEN * D_HEAD;
  float* __restrict__ outb =
      part + (size_t)z * CTX_ELEMS + (size_t)bh * S_LEN * D_HEAD;
  const int tid = threadIdx.x;

  if (tid < 128) inv_s[tid] = inv[(size_t)bh * S_LEN + mBase + tid];

  const int ty = (tid >> 4) << 3;  // m offset {0,8,...,120}, 16-lane broadcast
  const int tx = (tid & 15) << 2;  // d offset {0,4,...,60}, 2-way-free
  float acc[8][4] = {};
  const int kBeg = z * kLen;
  for (int kt = kBeg; kt < kBeg + kLen; kt += 32) {
    __syncthreads();  // protect LDS from previous iteration's readers
    // stage E 128 rows x 32 k: normalize, write back normalized, transpose
#pragma unroll
    for (int j = 0; j < 4; ++j) {
      const int f4 = tid + j * 256;   // 0..1023
      const int r = f4 >> 3;          // 0..127
      const int c4 = (f4 & 7) << 2;   // 0..28
      float* gp = Ab + (size_t)(mBase + r) * S_LEN + kt + c4;
      float4 e = *reinterpret_cast<const float4*>(gp);
      const float sc = inv_s[r];
      e.x *= sc; e.y *= sc; e.z *= sc; e.w *= sc;
      *reinterpret_cast<float4*>(gp) = e;  // normalized attn write-back
      Es[c4 + 0][r] = e.x; Es[c4 + 1][r] = e.y;
      Es[c4 + 2][r] = e.z; Es[c4 + 3][r] = e.w;
    }
    // stage V 32 k x 64 d, natural layout
#pragma unroll
    for (int j = 0; j < 2; ++j) {
      const int f4 = tid + j * 256;   // 0..511
      const int r = f4 >> 4;          // 0..31
      const int c0 = (f4 & 15) << 2;
      *reinterpret_cast<float4*>(&Vs[r][c0]) =
          *reinterpret_cast<const float4*>(Vb + (size_t)(kt + r) * D_HEAD + c0);
    }
    __syncthreads();
#pragma unroll 4
    for (int k = 0; k < 32; ++k) {
      const float4 a0 = *reinterpret_cast<const float4*>(&Es[k][ty]);
      const float4 a1 = *reinterpret_cast<const float4*>(&Es[k][ty + 4]);
      const float4 v = *reinterpret_cast<const float4*>(&Vs[k][tx]);
      const float av[8] = {a0.x, a0.y, a0.z, a0.w, a1.x, a1.y, a1.z, a1.w};
      const float vv[4] = {v.x, v.y, v.z, v.w};
#pragma unroll
      for (int i = 0; i < 8; ++i)
#pragma unroll
        for (int j = 0; j < 4; ++j)
          acc[i][j] = fmaf(av[i], vv[j], acc[i][j]);
    }
  }
#pragma unroll
  for (int i = 0; i < 8; ++i) {
    const float4 o = {acc[i][0], acc[i][1], acc[i][2], acc[i][3]};
    *reinterpret_cast<float4*>(outb + (size_t)(mBase + ty + i) * D_HEAD + tx) =
        o;
  }
}

// ---------------------------------------------------------------------------
// Kernel 4: ctx = sum over k-split partials (only when split > 1)
// ---------------------------------------------------------------------------
__global__ __launch_bounds__(256) void combine_kernel(
    const float* __restrict__ part, float* __restrict__ ctx, int split) {
  const size_t i = ((size_t)blockIdx.x * 256 + threadIdx.x) * 4;
  float4 s = {0.f, 0.f, 0.f, 0.f};
  for (int z = 0; z < split; ++z) {
    const float4 a = *reinterpret_cast<const float4*>(part + (size_t)z * CTX_ELEMS + i);
    s.x += a.x; s.y += a.y; s.z += a.z; s.w += a.w;
  }
  *reinterpret_cast<float4*>(ctx + i) = s;
}

extern "C" void kernel_launch(void* const* d_in, const int* in_sizes, int n_in,
                              void* d_out, int out_size, void* d_ws, size_t ws_size,
                              hipStream_t stream) {
  const float* Q = (const float*)d_in[0];
  const float* K = (const float*)d_in[1];
  const float* V = (const float*)d_in[2];
  const void* mask = d_in[3];  // jax bool: bytes or int32 — auto-detected

  float* ctx = (float*)d_out;               // [B,H,S,D]
  float* attn = (float*)d_out + CTX_ELEMS;  // [B,H,S,S]
  float* psum = ctx;                        // 2MB scratch inside ctx region

  float* inv = (float*)d_ws;                     // 128 KB
  int* mflag = (int*)((char*)d_ws + NROWS * 4);  // 4 B
  const size_t partOff = (size_t)NROWS * 4 + 256;
  float* part = (float*)((char*)d_ws + partOff);

  // k-split factor from available workspace (ws_size constant per session =>
  // identical work every call, graph-capture safe)
  int split = 1;
  if (ws_size >= partOff + 4ull * CTX_ELEMS * 4) split = 4;
  else if (ws_size >= partOff + 2ull * CTX_ELEMS * 4) split = 2;
  float* pvOut = (split > 1) ? part : ctx;

  detect_mask_kernel<<<1, 256, 0, stream>>>((const uint32_t*)mask, mflag);
  qk_exp_kernel<<<dim3(S_LEN / 128, S_LEN / 128, NBH), 256, 0, stream>>>(
      Q, K, mask, attn, psum, mflag);
  row_inv_kernel<<<NROWS / 256, 256, 0, stream>>>(psum, inv);
  pv_kernel<<<dim3(S_LEN / 128, NBH, split), 256, 0, stream>>>(
      attn, V, inv, pvOut, S_LEN / split);
  if (split > 1)
    combine_kernel<<<CTX_ELEMS / 4 / 256, 256, 0, stream>>>(part, ctx, split);
}

// Round 5
// 644.564 us; speedup vs baseline: 1.6611x; 1.0330x over previous
//
#include <hip/hip_runtime.h>
#include <stdint.h>

#define S_LEN 2048
#define D_HEAD 64
#define NBH 16
#define NROWS (NBH * S_LEN)               // 32768 attention rows
#define CTX_ELEMS (NBH * S_LEN * D_HEAD)  // 2,097,152 floats

// d_out layout: [ctx 8MB][attn 268MB].
// ws layout: [psum 2MB][pad][pv k-split partials split*8MB]. (ws observed ~1 GB)

// ---------------------------------------------------------------------------
// Kernel 1: e = exp((Q.K^T)/8) (0 where masked), unnormalized, into the attn
// region; per-(row, 128-col-block) partial sums into psum (ws).
// 128x128 tile, 256 threads, 8x8 micro, two 32-d LDS phases.
// New vs r4: per-block mask-dtype detect (no separate kernel) and mask words
// hoisted into registers before the phase-2 compute (kills the 8 serial
// ~900cy dependent mask-load latencies in the epilogue).
// ---------------------------------------------------------------------------
__global__ __launch_bounds__(256, 3) void qk_exp_kernel(
    const float* __restrict__ Q, const float* __restrict__ K,
    const void* __restrict__ mask, float* __restrict__ e_out,
    float* __restrict__ psum) {
  __shared__ float Qs[32][132];
  __shared__ float Ks[32][132];
  __shared__ int s_bytes;
  const int bh = blockIdx.z;
  const int mBase = blockIdx.y * 128;
  const int nBase = blockIdx.x * 128;
  const float* __restrict__ Qb = Q + (size_t)bh * S_LEN * D_HEAD;
  const float* __restrict__ Kb = K + (size_t)bh * S_LEN * D_HEAD;
  float* __restrict__ Eb = e_out + (size_t)bh * S_LEN * S_LEN;
  const int tid = threadIdx.x;

  // --- per-block mask dtype detect: scan 1KB of own region as u32; any
  // word > 1 => byte layout (P[miss] = 0.729^256 ~ e^-81 at 10% density).
  if (tid == 0) s_bytes = 0;
  __syncthreads();
  {
    const uint32_t* mw = (const uint32_t*)((const uint8_t*)mask +
                                           ((size_t)bh * S_LEN + mBase) * S_LEN);
    if (mw[tid] > 1u) atomicOr(&s_bytes, 1);
  }

  const int ty = (tid >> 4) << 3;  // rows: 8 contiguous (16-lane broadcast)
  const int cj = (tid & 15) << 2;  // cols: cj and 64+cj (2-way-free b128)
  float acc[8][8] = {};

  // ---- phase 0 stage (d = 0..31)
#pragma unroll
  for (int i = 0; i < 4; ++i) {
    const int f4 = tid + i * 256;
    const int row = f4 >> 3;
    const int d0 = (f4 & 7) << 2;
    const float4 qv = *reinterpret_cast<const float4*>(
        Qb + (size_t)(mBase + row) * D_HEAD + d0);
    const float4 kv = *reinterpret_cast<const float4*>(
        Kb + (size_t)(nBase + row) * D_HEAD + d0);
    Qs[d0 + 0][row] = qv.x; Qs[d0 + 1][row] = qv.y;
    Qs[d0 + 2][row] = qv.z; Qs[d0 + 3][row] = qv.w;
    Ks[d0 + 0][row] = kv.x; Ks[d0 + 1][row] = kv.y;
    Ks[d0 + 2][row] = kv.z; Ks[d0 + 3][row] = kv.w;
  }
  __syncthreads();
  const int maskBytes = s_bytes;

#pragma unroll 4
  for (int d = 0; d < 32; ++d) {
    const float4 q0 = *reinterpret_cast<const float4*>(&Qs[d][ty]);
    const float4 q1 = *reinterpret_cast<const float4*>(&Qs[d][ty + 4]);
    const float4 kl = *reinterpret_cast<const float4*>(&Ks[d][cj]);
    const float4 kh = *reinterpret_cast<const float4*>(&Ks[d][64 + cj]);
    const float qv[8] = {q0.x, q0.y, q0.z, q0.w, q1.x, q1.y, q1.z, q1.w};
    const float kv[8] = {kl.x, kl.y, kl.z, kl.w, kh.x, kh.y, kh.z, kh.w};
#pragma unroll
    for (int i = 0; i < 8; ++i)
#pragma unroll
      for (int j = 0; j < 8; ++j)
        acc[i][j] = fmaf(qv[i], kv[j], acc[i][j]);
  }
  __syncthreads();

  // ---- phase 1 stage (d = 32..63)
#pragma unroll
  for (int i = 0; i < 4; ++i) {
    const int f4 = tid + i * 256;
    const int row = f4 >> 3;
    const int d0 = (f4 & 7) << 2;
    const float4 qv = *reinterpret_cast<const float4*>(
        Qb + (size_t)(mBase + row) * D_HEAD + 32 + d0);
    const float4 kv = *reinterpret_cast<const float4*>(
        Kb + (size_t)(nBase + row) * D_HEAD + 32 + d0);
    Qs[d0 + 0][row] = qv.x; Qs[d0 + 1][row] = qv.y;
    Qs[d0 + 2][row] = qv.z; Qs[d0 + 3][row] = qv.w;
    Ks[d0 + 0][row] = kv.x; Ks[d0 + 1][row] = kv.y;
    Ks[d0 + 2][row] = kv.z; Ks[d0 + 3][row] = kv.w;
  }
  __syncthreads();

  // ---- hoisted mask loads: issued here, consumed after the 4096-cy compute
  uint32_t mlv[8], mhv[8];
  if (maskBytes) {
#pragma unroll
    for (int i = 0; i < 8; ++i) {
      const unsigned char* mrow = (const unsigned char*)mask +
          ((size_t)bh * S_LEN + mBase + ty + i) * S_LEN + nBase;
      mlv[i] = *reinterpret_cast<const uint32_t*>(mrow + cj);
      mhv[i] = *reinterpret_cast<const uint32_t*>(mrow + 64 + cj);
    }
  } else {
    // rare path: int32 mask — load+pack to per-row bitmask immediately
#pragma unroll
    for (int i = 0; i < 8; ++i) {
      const int* mrow = (const int*)mask +
          ((size_t)bh * S_LEN + mBase + ty + i) * S_LEN + nBase;
      const int4 m0 = *reinterpret_cast<const int4*>(mrow + cj);
      const int4 m1 = *reinterpret_cast<const int4*>(mrow + 64 + cj);
      uint32_t b = 0;
      b |= (m0.x ? 0x001u : 0) | (m0.y ? 0x100u : 0) |
           (m0.z ? 0x10000u : 0) | (m0.w ? 0x1000000u : 0);
      mlv[i] = b;
      b = 0;
      b |= (m1.x ? 0x001u : 0) | (m1.y ? 0x100u : 0) |
           (m1.z ? 0x10000u : 0) | (m1.w ? 0x1000000u : 0);
      mhv[i] = b;
    }
  }

#pragma unroll 4
  for (int d = 0; d < 32; ++d) {
    const float4 q0 = *reinterpret_cast<const float4*>(&Qs[d][ty]);
    const float4 q1 = *reinterpret_cast<const float4*>(&Qs[d][ty + 4]);
    const float4 kl = *reinterpret_cast<const float4*>(&Ks[d][cj]);
    const float4 kh = *reinterpret_cast<const float4*>(&Ks[d][64 + cj]);
    const float qv[8] = {q0.x, q0.y, q0.z, q0.w, q1.x, q1.y, q1.z, q1.w};
    const float kv[8] = {kl.x, kl.y, kl.z, kl.w, kh.x, kh.y, kh.z, kh.w};
#pragma unroll
    for (int i = 0; i < 8; ++i)
#pragma unroll
      for (int j = 0; j < 8; ++j)
        acc[i][j] = fmaf(qv[i], kv[j], acc[i][j]);
  }

  const float scale = 0.125f;  // 1/sqrt(64)
#pragma unroll
  for (int i = 0; i < 8; ++i) {
    const int row = mBase + ty + i;
    float e[8];
#pragma unroll
    for (int j = 0; j < 4; ++j) {
      e[j] = ((mlv[i] >> (8 * j)) & 0xffu) ? 0.0f : __expf(acc[i][j] * scale);
      e[4 + j] =
          ((mhv[i] >> (8 * j)) & 0xffu) ? 0.0f : __expf(acc[i][4 + j] * scale);
    }
    const float4 o0 = {e[0], e[1], e[2], e[3]};
    const float4 o1 = {e[4], e[5], e[6], e[7]};
    float* dst = Eb + (size_t)row * S_LEN + nBase;
    *reinterpret_cast<float4*>(dst + cj) = o0;
    *reinterpret_cast<float4*>(dst + 64 + cj) = o1;

    float r = (e[0] + e[1] + e[2] + e[3]) + (e[4] + e[5] + e[6] + e[7]);
    r += __shfl_xor(r, 1, 64);
    r += __shfl_xor(r, 2, 64);
    r += __shfl_xor(r, 4, 64);
    r += __shfl_xor(r, 8, 64);
    if ((tid & 15) == 0)
      psum[((size_t)bh * S_LEN + row) * 16 + blockIdx.x] = r;
  }
}

// ---------------------------------------------------------------------------
// Kernel 2: PV GEMM fused with per-block inv computation, normalization and
// normalized-attn write-back. Tile M=128 x N=64, K-step 32, 256 threads,
// 8x4 micro. T14 async-split: tile t+1 register-prefetched during tile t's
// compute (HBM latency hides under the 2048-cy FMA phase).
// ---------------------------------------------------------------------------
__global__ __launch_bounds__(256, 3) void pv_kernel(
    float* __restrict__ attn, const float* __restrict__ V,
    const float* __restrict__ psum, float* __restrict__ outp, int kLen) {
  __shared__ float Es[32][132];  // [k][m] transposed
  __shared__ float Vs[32][68];   // [k][d] natural
  __shared__ float inv_s[128];
  const int bh = blockIdx.y;
  const int mBase = blockIdx.x * 128;
  const int z = blockIdx.z;
  float* __restrict__ Ab = attn + (size_t)bh * S_LEN * S_LEN;
  const float* __restrict__ Vb = V + (size_t)bh * S_LEN * D_HEAD;
  float* __restrict__ outb =
      outp + (size_t)z * CTX_ELEMS + (size_t)bh * S_LEN * D_HEAD;
  const int tid = threadIdx.x;

  // per-block inv from psum (replaces the row_inv kernel)
  if (tid < 128) {
    const float4* p = reinterpret_cast<const float4*>(
        psum + ((size_t)bh * S_LEN + mBase + tid) * 16);
    const float4 a = p[0], b = p[1], c = p[2], d = p[3];
    inv_s[tid] =
        1.0f / (((a.x + a.y) + (a.z + a.w)) + ((b.x + b.y) + (b.z + b.w)) +
                ((c.x + c.y) + (c.z + c.w)) + ((d.x + d.y) + (d.z + d.w)));
  }

  const int rr = tid >> 3;         // 0..31 (E stage row within 32-row group)
  const int c4 = (tid & 7) << 2;   // 0..28 (E stage k-offset)
  const int vr = tid >> 4;         // 0..15 (V stage row within 16-row group)
  const int vc = (tid & 15) << 2;  // 0..60 (V stage d-offset)
  const int ty = (tid >> 4) << 3;  // 0..120 compute m-offset
  const int tx = (tid & 15) << 2;  // 0..60 compute d-offset

  const int kBeg = z * kLen;
  const int nT = kLen / 32;

  // prefetch tile 0
  float4 er[4], vv[2];
#pragma unroll
  for (int j = 0; j < 4; ++j)
    er[j] = *reinterpret_cast<const float4*>(
        Ab + (size_t)(mBase + 32 * j + rr) * S_LEN + kBeg + c4);
#pragma unroll
  for (int j = 0; j < 2; ++j)
    vv[j] = *reinterpret_cast<const float4*>(
        Vb + (size_t)(kBeg + 16 * j + vr) * D_HEAD + vc);

  float acc[8][4] = {};
  for (int t = 0; t < nT; ++t) {
    const int kt = kBeg + t * 32;
    __syncthreads();  // prev tile's LDS consumers done; iter0: inv_s ready
    // write phase: normalize from regs, write back normalized attn, fill LDS
#pragma unroll
    for (int j = 0; j < 4; ++j) {
      const int r = 32 * j + rr;
      const float sc = inv_s[r];
      float4 e = er[j];
      e.x *= sc; e.y *= sc; e.z *= sc; e.w *= sc;
      *reinterpret_cast<float4*>(Ab + (size_t)(mBase + r) * S_LEN + kt + c4) = e;
      Es[c4 + 0][r] = e.x; Es[c4 + 1][r] = e.y;
      Es[c4 + 2][r] = e.z; Es[c4 + 3][r] = e.w;
    }
#pragma unroll
    for (int j = 0; j < 2; ++j)
      *reinterpret_cast<float4*>(&Vs[16 * j + vr][vc]) = vv[j];
    // prefetch tile t+1 (lands during compute)
    if (t + 1 < nT) {
      const int kn = kt + 32;
#pragma unroll
      for (int j = 0; j < 4; ++j)
        er[j] = *reinterpret_cast<const float4*>(
            Ab + (size_t)(mBase + 32 * j + rr) * S_LEN + kn + c4);
#pragma unroll
      for (int j = 0; j < 2; ++j)
        vv[j] = *reinterpret_cast<const float4*>(
            Vb + (size_t)(kn + 16 * j + vr) * D_HEAD + vc);
    }
    __syncthreads();
    // compute phase
#pragma unroll 4
    for (int k = 0; k < 32; ++k) {
      const float4 a0 = *reinterpret_cast<const float4*>(&Es[k][ty]);
      const float4 a1 = *reinterpret_cast<const float4*>(&Es[k][ty + 4]);
      const float4 v = *reinterpret_cast<const float4*>(&Vs[k][tx]);
      const float av[8] = {a0.x, a0.y, a0.z, a0.w, a1.x, a1.y, a1.z, a1.w};
#pragma unroll
      for (int i = 0; i < 8; ++i) {
        acc[i][0] = fmaf(av[i], v.x, acc[i][0]);
        acc[i][1] = fmaf(av[i], v.y, acc[i][1]);
        acc[i][2] = fmaf(av[i], v.z, acc[i][2]);
        acc[i][3] = fmaf(av[i], v.w, acc[i][3]);
      }
    }
  }
#pragma unroll
  for (int i = 0; i < 8; ++i) {
    const float4 o = {acc[i][0], acc[i][1], acc[i][2], acc[i][3]};
    *reinterpret_cast<float4*>(outb + (size_t)(mBase + ty + i) * D_HEAD + tx) =
        o;
  }
}

// ---------------------------------------------------------------------------
// Kernel 3: ctx = sum over k-split partials (only when split > 1)
// ---------------------------------------------------------------------------
__global__ __launch_bounds__(256) void combine_kernel(
    const float* __restrict__ part, float* __restrict__ ctx, int split) {
  const size_t i = ((size_t)blockIdx.x * 256 + threadIdx.x) * 4;
  float4 s = {0.f, 0.f, 0.f, 0.f};
  for (int z = 0; z < split; ++z) {
    const float4 a =
        *reinterpret_cast<const float4*>(part + (size_t)z * CTX_ELEMS + i);
    s.x += a.x; s.y += a.y; s.z += a.z; s.w += a.w;
  }
  *reinterpret_cast<float4*>(ctx + i) = s;
}

extern "C" void kernel_launch(void* const* d_in, const int* in_sizes, int n_in,
                              void* d_out, int out_size, void* d_ws, size_t ws_size,
                              hipStream_t stream) {
  const float* Q = (const float*)d_in[0];
  const float* K = (const float*)d_in[1];
  const float* V = (const float*)d_in[2];
  const void* mask = d_in[3];  // jax bool: bytes or int32 — per-block detected

  float* ctx = (float*)d_out;               // [B,H,S,D]
  float* attn = (float*)d_out + CTX_ELEMS;  // [B,H,S,S]

  float* psum = (float*)d_ws;  // [NROWS][16] partial row sums, 2 MB
  const size_t partOff = ((size_t)NROWS * 16 * 4 + 255) & ~(size_t)255;
  float* part = (float*)((char*)d_ws + partOff);

  // k-split from available ws (ws_size constant per session => same work
  // every call; graph-capture safe). Observed ws ~1 GB => split=4.
  int split = 1;
  if (ws_size >= partOff + 4ull * CTX_ELEMS * 4) split = 4;
  else if (ws_size >= partOff + 2ull * CTX_ELEMS * 4) split = 2;
  float* pvOut = (split > 1) ? part : ctx;

  qk_exp_kernel<<<dim3(S_LEN / 128, S_LEN / 128, NBH), 256, 0, stream>>>(
      Q, K, mask, attn, psum);
  pv_kernel<<<dim3(S_LEN / 128, NBH, split), 256, 0, stream>>>(
      attn, V, psum, pvOut, S_LEN / split);
  if (split > 1)
    combine_kernel<<<CTX_ELEMS / 4 / 256, 256, 0, stream>>>(part, ctx, split);
}